// Round 1
// baseline (926.196 us; speedup 1.0000x reference)
//
#include <hip/hip_runtime.h>
#include <hip/hip_bf16.h>
#include <math.h>

typedef float v4f __attribute__((ext_vector_type(4)));
typedef short v8s __attribute__((ext_vector_type(8)));
typedef short v4s __attribute__((ext_vector_type(4)));

#define NBATCH 4096
#define NT 64
#define HD 256
#define UD 128
#define ZD 16
#define AD 64
#define LRSCALE 0.25f

// output offsets (floats) in d_out: c, z_next, attn, q, k, v
#define OFF_C    0UL
#define OFF_ZN   33554432UL
#define OFF_ATTN 37748736UL
#define OFF_Q    54525952UL
#define OFF_K    71303168UL
#define OFF_V    88080384UL

__device__ __forceinline__ short f2bf(float x) {
  unsigned u = __float_as_uint(x);
  u = (u + 0x7fffu + ((u >> 16) & 1u)) >> 16;  // RNE
  return (short)u;
}
__device__ __forceinline__ v8s ld8(const short* p) { return *(const v8s*)p; }

// One workgroup per batch. 256 threads = 4 waves.
// LDS overlay offsets inside scr[49152]:
//  P1: WT1[48][296] @0 (28416B), Ach[64][32] @28416 (4096B)
//  P2: WT2[16][136] @0 (4352B), Ach reused
//  P3: q_s[64][72] @0, k_s @9216, vT @18432 (each 9216B)
//  P4: attnF f32[64][66] @0 (16896B, overlays q/k after GEMM3), attnB[64][72] @27648
//  P5: clB[64][72] @0
//  P6: WoT[128][72] @9216 (18432B), cB[64][136] @27648 (17408B)
//  P7: WcT[32][136] @0 (8704B)
__global__ __launch_bounds__(256, 2)
void memetic_fused(
    const float* __restrict__ hg, const float* __restrict__ ug2,
    const float* __restrict__ zg,
    const float* __restrict__ qd_down, const float* __restrict__ qd_up,
    const float* __restrict__ kd_down, const float* __restrict__ kd_up,
    const float* __restrict__ vd_down, const float* __restrict__ vd_up,
    const float* __restrict__ od_down, const float* __restrict__ od_up,
    const float* __restrict__ ug_w, const float* __restrict__ ug_b,
    const float* __restrict__ cand_w, const float* __restrict__ cand_b,
    const float* __restrict__ eta_logit,
    float* __restrict__ c_o, float* __restrict__ zn_o,
    float* __restrict__ attn_o, float* __restrict__ q_o,
    float* __restrict__ k_o, float* __restrict__ v_o)
{
  __shared__ float z_s[NT * ZD];    // 4 KB, persists whole kernel
  __shared__ float g1out[NT * 33];  // gate_pre[0..15], cand_pre[16..31] (z+h parts, then +c)
  __shared__ float qkv4[NT * 13];   // qd4[0..3], kd4[4..7], vd4[8..11]
  __shared__ char scr[49152];

  const int b = blockIdx.x;
  const int tid = threadIdx.x;
  const int lane = tid & 63;
  const int wv = tid >> 6;      // wave 0..3
  const int quad = lane >> 4;   // 0..3
  const int l16 = lane & 15;

  // ---------- P0: load z ----------
  ((v4f*)z_s)[tid] = ((const v4f*)(zg + (size_t)b * (NT * ZD)))[tid];

  // ---------- P1: GEMM1  A=[h|z] (K=272 pad 288), N=48: [qd4(4)+pad | gate(16) | cand(16)] ----------
  short* WT1 = (short*)scr;            // [48][296] bf16, row n = output col, B[k][n] transposed
  short* Ach = (short*)(scr + 28416);  // [64][32] bf16, one K-chunk
  for (int idx = tid; idx < 48 * 296; idx += 256) {
    int n = idx / 296, k = idx - n * 296;
    float val = 0.f;
    if (k < 288) {
      if (n < 4) {
        if (k < 272) val = qd_down[k * 4 + n];           // q_in=[h,z] matches qd_down rows
      } else if (n >= 16) {
        const float* W = (n < 32) ? ug_w : cand_w;       // mix=[z,h,c]: z rows 0..15, h rows 16..271
        int o = (n < 32) ? (n - 16) : (n - 32);
        if (k < 256) val = W[(16 + k) * 16 + o];         // h dims
        else if (k < 272) val = W[(k - 256) * 16 + o];   // z dims
      }
    }
    WT1[idx] = f2bf(val);
  }

  v4f acc1[3];
  for (int i = 0; i < 3; ++i) acc1[i] = (v4f){0.f, 0.f, 0.f, 0.f};
  const int stok = tid >> 2;          // staging: token 0..63
  const int skg = (tid & 3) * 4;      // k sub-offset 0,4,8,12

  for (int kc = 0; kc < 9; ++kc) {
#pragma unroll
    for (int ki = 0; ki < 2; ++ki) {
      int kk = kc * 32 + ki * 16 + skg;  // global K index 0..287
      v4f hv;
      if (kc < 8) {
        hv = *(const v4f*)(hg + ((size_t)b * NT + stok) * HD + kk);
      } else {
        int kz = kk - 256;
        if (kz < 16) hv = *(const v4f*)(z_s + stok * ZD + kz);
        else hv = (v4f){0.f, 0.f, 0.f, 0.f};
      }
      v4s w;
      w.x = f2bf(hv.x); w.y = f2bf(hv.y); w.z = f2bf(hv.z); w.w = f2bf(hv.w);
      *(v4s*)(Ach + stok * 32 + ki * 16 + skg) = w;
    }
    __syncthreads();
    v8s a = ld8(Ach + (wv * 16 + l16) * 32 + quad * 8);  // A[m][k]: m=l16(+16*mt), k=quad*8+j
#pragma unroll
    for (int nt = 0; nt < 3; ++nt) {
      v8s bb = ld8(WT1 + (nt * 16 + l16) * 296 + kc * 32 + quad * 8);  // B[k][n] from BT[n][k]
      acc1[nt] = __builtin_amdgcn_mfma_f32_16x16x32_bf16(a, bb, acc1[nt], 0, 0, 0);
    }
    __syncthreads();
  }
  // C/D layout: col = l16, row = quad*4 + r; this wave's M-tile = wv
  if (l16 < 4) {
#pragma unroll
    for (int r = 0; r < 4; ++r)
      qkv4[(wv * 16 + quad * 4 + r) * 13 + l16] = acc1[0][r];
  }
#pragma unroll
  for (int r = 0; r < 4; ++r) {
    int row = wv * 16 + quad * 4 + r;
    g1out[row * 33 + l16] = acc1[1][r];
    g1out[row * 33 + 16 + l16] = acc1[2][r];
  }

  // ---------- P2: GEMM2  A=u (K=128), N=16: [kd4(4) vd4(4) pad(8)] ----------
  short* WT2 = (short*)scr;  // [16][136]
  for (int idx = tid; idx < 16 * 136; idx += 256) {
    int n = idx / 136, k = idx - n * 136;
    float val = 0.f;
    if (k < 128) {
      if (n < 4) val = kd_down[k * 4 + n];
      else if (n < 8) val = vd_down[k * 4 + (n - 4)];
    }
    WT2[idx] = f2bf(val);
  }
  v4f acc2 = (v4f){0.f, 0.f, 0.f, 0.f};
  for (int kc = 0; kc < 4; ++kc) {
#pragma unroll
    for (int ki = 0; ki < 2; ++ki) {
      int kk = kc * 32 + ki * 16 + skg;
      v4f uv = *(const v4f*)(ug2 + ((size_t)b * NT + stok) * UD + kk);
      v4s w;
      w.x = f2bf(uv.x); w.y = f2bf(uv.y); w.z = f2bf(uv.z); w.w = f2bf(uv.w);
      *(v4s*)(Ach + stok * 32 + ki * 16 + skg) = w;
    }
    __syncthreads();
    v8s a = ld8(Ach + (wv * 16 + l16) * 32 + quad * 8);
    v8s bb = ld8(WT2 + l16 * 136 + kc * 32 + quad * 8);
    acc2 = __builtin_amdgcn_mfma_f32_16x16x32_bf16(a, bb, acc2, 0, 0, 0);
    __syncthreads();
  }
  if (l16 < 8) {
#pragma unroll
    for (int r = 0; r < 4; ++r)
      qkv4[(wv * 16 + quad * 4 + r) * 13 + 4 + l16] = acc2[r];
  }
  __syncthreads();

  // ---------- P3: expand q,k,v = rank4 @ up * SCALE; write global f32 + LDS bf16 ----------
  {
    short* q_s = (short*)scr;
    short* k_s = (short*)(scr + 9216);
    short* vT = (short*)(scr + 18432);
    float qup[4], kup[4], vup[4];
#pragma unroll
    for (int r = 0; r < 4; ++r) {
      qup[r] = qd_up[r * AD + lane];
      kup[r] = kd_up[r * AD + lane];
      vup[r] = vd_up[r * AD + lane];
    }
    for (int i = 0; i < 16; ++i) {
      int t = wv * 16 + i;
      const float* p4 = qkv4 + t * 13;
      float qv = LRSCALE * (p4[0] * qup[0] + p4[1] * qup[1] + p4[2] * qup[2] + p4[3] * qup[3]);
      float kv = LRSCALE * (p4[4] * kup[0] + p4[5] * kup[1] + p4[6] * kup[2] + p4[7] * kup[3]);
      float vv = LRSCALE * (p4[8] * vup[0] + p4[9] * vup[1] + p4[10] * vup[2] + p4[11] * vup[3]);
      size_t go = ((size_t)b * NT + t) * AD + lane;
      q_o[go] = qv; k_o[go] = kv; v_o[go] = vv;
      q_s[t * 72 + lane] = f2bf(qv);
      k_s[t * 72 + lane] = f2bf(kv);
      vT[lane * 72 + t] = f2bf(vv);   // transposed for PV B-operand
    }
  }
  __syncthreads();

  // ---------- P4: scores = q @ k^T / 8, diag mask, softmax ----------
  v4f acc3[4];
  for (int i = 0; i < 4; ++i) acc3[i] = (v4f){0.f, 0.f, 0.f, 0.f};
  {
    short* q_s = (short*)scr;
    short* k_s = (short*)(scr + 9216);
#pragma unroll
    for (int kc = 0; kc < 2; ++kc) {
      v8s bb = ld8(k_s + (wv * 16 + l16) * 72 + kc * 32 + quad * 8);  // B[d][m]=k[m][d]
#pragma unroll
      for (int mt = 0; mt < 4; ++mt) {
        v8s a = ld8(q_s + (mt * 16 + l16) * 72 + kc * 32 + quad * 8);
        acc3[mt] = __builtin_amdgcn_mfma_f32_16x16x32_bf16(a, bb, acc3[mt], 0, 0, 0);
      }
    }
  }
  __syncthreads();
  {
    float* attnF = (float*)scr;  // [64][66], overlays q/k (dead)
#pragma unroll
    for (int mt = 0; mt < 4; ++mt)
#pragma unroll
      for (int r = 0; r < 4; ++r) {
        int row = mt * 16 + quad * 4 + r;
        int col = wv * 16 + l16;
        float s = acc3[mt][r] * 0.125f;
        attnF[row * 66 + col] = (row == col) ? -INFINITY : s;
      }
  }
  __syncthreads();
  {
    float* attnF = (float*)scr;
    short* attnB = (short*)(scr + 27648);
    int n = tid >> 2, p = tid & 3;
    float e[16];
    float mx = -INFINITY;
    const float* rp = attnF + n * 66 + p * 16;
#pragma unroll
    for (int i = 0; i < 16; ++i) { e[i] = rp[i]; mx = fmaxf(mx, e[i]); }
    mx = fmaxf(mx, __shfl_xor(mx, 1));
    mx = fmaxf(mx, __shfl_xor(mx, 2));
    float s = 0.f;
#pragma unroll
    for (int i = 0; i < 16; ++i) { float ee = __expf(e[i] - mx); e[i] = ee; s += ee; }
    s += __shfl_xor(s, 1);
    s += __shfl_xor(s, 2);
    float inv = 1.f / s;
    size_t gb = ((size_t)b * NT + n) * NT + p * 16;
#pragma unroll
    for (int i = 0; i < 16; ++i) {
      float av = e[i] * inv;          // diag: exp(-inf)=0 -> exact 0
      attn_o[gb + i] = av;
      attnB[n * 72 + p * 16 + i] = f2bf(av);
    }
  }
  __syncthreads();

  // ---------- P5: c_latent = attn @ v ----------
  v4f acc4[4];
  for (int i = 0; i < 4; ++i) acc4[i] = (v4f){0.f, 0.f, 0.f, 0.f};
  {
    short* attnB = (short*)(scr + 27648);
    short* vT = (short*)(scr + 18432);
#pragma unroll
    for (int kc = 0; kc < 2; ++kc) {
      v8s bb = ld8(vT + (wv * 16 + l16) * 72 + kc * 32 + quad * 8);  // B[m][d]=vT[d][m]
#pragma unroll
      for (int mt = 0; mt < 4; ++mt) {
        v8s a = ld8(attnB + (mt * 16 + l16) * 72 + kc * 32 + quad * 8);
        acc4[mt] = __builtin_amdgcn_mfma_f32_16x16x32_bf16(a, bb, acc4[mt], 0, 0, 0);
      }
    }
  }
  {
    short* clB = (short*)scr;  // [64][72], overlays attnF (dead)
#pragma unroll
    for (int mt = 0; mt < 4; ++mt)
#pragma unroll
      for (int r = 0; r < 4; ++r)
        clB[(mt * 16 + quad * 4 + r) * 72 + wv * 16 + l16] = f2bf(acc4[mt][r]);
  }
  __syncthreads();  // GEMM4 reads done before WoT overwrites vT region

  // ---------- P6: c = c_latent @ (od_down @ od_up * SCALE) ----------
  {
    short* WoT = (short*)(scr + 9216);  // [128][72]: WoT[e][d]
    for (int idx = tid; idx < 128 * 64; idx += 256) {
      int d = idx & 63, e2 = idx >> 6;
      float a = od_down[d * 4 + 0] * od_up[e2] + od_down[d * 4 + 1] * od_up[128 + e2]
              + od_down[d * 4 + 2] * od_up[256 + e2] + od_down[d * 4 + 3] * od_up[384 + e2];
      WoT[e2 * 72 + d] = f2bf(a * LRSCALE);
    }
  }
  __syncthreads();
  v4f acc5[4][2];
  for (int i = 0; i < 4; ++i)
    for (int j = 0; j < 2; ++j) acc5[i][j] = (v4f){0.f, 0.f, 0.f, 0.f};
  {
    short* clB = (short*)scr;
    short* WoT = (short*)(scr + 9216);
#pragma unroll
    for (int kc = 0; kc < 2; ++kc)
#pragma unroll
      for (int mt = 0; mt < 4; ++mt) {
        v8s a = ld8(clB + (mt * 16 + l16) * 72 + kc * 32 + quad * 8);
#pragma unroll
        for (int j = 0; j < 2; ++j) {
          v8s bb = ld8(WoT + ((wv + 4 * j) * 16 + l16) * 72 + kc * 32 + quad * 8);
          acc5[mt][j] = __builtin_amdgcn_mfma_f32_16x16x32_bf16(a, bb, acc5[mt][j], 0, 0, 0);
        }
      }
  }
  {
    short* cB = (short*)(scr + 27648);  // [64][136]
#pragma unroll
    for (int mt = 0; mt < 4; ++mt)
#pragma unroll
      for (int j = 0; j < 2; ++j)
#pragma unroll
        for (int r = 0; r < 4; ++r) {
          int row = mt * 16 + quad * 4 + r;
          int e2 = (wv + 4 * j) * 16 + l16;
          float val = acc5[mt][j][r];
          c_o[((size_t)b * NT + row) * UD + e2] = val;
          cB[row * 136 + e2] = f2bf(val);
        }
  }
  __syncthreads();

  // ---------- P7: gate/cand c-part: c @ W[272:400] added into g1out ----------
  {
    short* WcT = (short*)scr;  // [32][136]
    for (int idx = tid; idx < 32 * 128; idx += 256) {
      int o = idx >> 7, e2 = idx & 127;
      const float* W = (o < 16) ? ug_w : cand_w;
      WcT[o * 136 + e2] = f2bf(W[(272 + e2) * 16 + (o & 15)]);
    }
  }
  __syncthreads();
  v4f acc6[2];
  for (int i = 0; i < 2; ++i) acc6[i] = (v4f){0.f, 0.f, 0.f, 0.f};
  {
    short* cB = (short*)(scr + 27648);
    short* WcT = (short*)scr;
#pragma unroll
    for (int kc = 0; kc < 4; ++kc) {
      v8s a = ld8(cB + (wv * 16 + l16) * 136 + kc * 32 + quad * 8);
#pragma unroll
      for (int nt = 0; nt < 2; ++nt) {
        v8s bb = ld8(WcT + (nt * 16 + l16) * 136 + kc * 32 + quad * 8);
        acc6[nt] = __builtin_amdgcn_mfma_f32_16x16x32_bf16(a, bb, acc6[nt], 0, 0, 0);
      }
    }
  }
#pragma unroll
  for (int nt = 0; nt < 2; ++nt)
#pragma unroll
    for (int r = 0; r < 4; ++r) {
      int row = wv * 16 + quad * 4 + r;
      g1out[row * 33 + nt * 16 + l16] += acc6[nt][r];
    }
  __syncthreads();

  // ---------- P8: gated update + layernorm ----------
  if (tid < NT) {
    const int t = tid;
    float eta = 1.f / (1.f + __expf(-eta_logit[0]));
    float x[16];
    float mean = 0.f;
#pragma unroll
    for (int o = 0; o < 16; ++o) {
      float gpre = g1out[t * 33 + o] + ug_b[o];
      float cpre = g1out[t * 33 + 16 + o] + cand_b[o];
      float gate = 1.f / (1.f + __expf(-gpre));
      float prop = tanhf(cpre);
      float eg = eta * gate;
      float xv = (1.f - eg) * z_s[t * ZD + o] + eg * prop;
      x[o] = xv;
      mean += xv;
    }
    mean *= (1.f / 16.f);
    float var = 0.f;
#pragma unroll
    for (int o = 0; o < 16; ++o) { float d0 = x[o] - mean; var += d0 * d0; }
    var *= (1.f / 16.f);
    float rs = rsqrtf(var + 1e-5f);
#pragma unroll
    for (int o = 0; o < 16; ++o)
      zn_o[((size_t)b * NT + t) * ZD + o] = (x[o] - mean) * rs;
  }
}

extern "C" void kernel_launch(void* const* d_in, const int* in_sizes, int n_in,
                              void* d_out, int out_size, void* d_ws, size_t ws_size,
                              hipStream_t stream) {
  const float* h = (const float*)d_in[0];
  const float* u = (const float*)d_in[1];
  const float* z = (const float*)d_in[2];
  const float* qd_down = (const float*)d_in[3];
  const float* qd_up = (const float*)d_in[4];
  const float* kd_down = (const float*)d_in[5];
  const float* kd_up = (const float*)d_in[6];
  const float* vd_down = (const float*)d_in[7];
  const float* vd_up = (const float*)d_in[8];
  const float* od_down = (const float*)d_in[9];
  const float* od_up = (const float*)d_in[10];
  const float* ug_w = (const float*)d_in[11];
  const float* ug_b = (const float*)d_in[12];
  const float* cand_w = (const float*)d_in[13];
  const float* cand_b = (const float*)d_in[14];
  const float* eta_logit = (const float*)d_in[15];
  float* out = (float*)d_out;

  memetic_fused<<<NBATCH, 256, 0, stream>>>(
      h, u, z, qd_down, qd_up, kd_down, kd_up, vd_down, vd_up,
      od_down, od_up, ug_w, ug_b, cand_w, cand_b, eta_logit,
      out + OFF_C, out + OFF_ZN, out + OFF_ATTN,
      out + OFF_Q, out + OFF_K, out + OFF_V);
}